// Round 17
// baseline (209.079 us; speedup 1.0000x reference)
//
#include <hip/hip_runtime.h>

typedef unsigned int u32;
typedef unsigned short u16;
typedef unsigned char u8;
typedef _Float16 half8 __attribute__((ext_vector_type(8)));
typedef float f32x4 __attribute__((ext_vector_type(4)));
typedef float f32x2 __attribute__((ext_vector_type(2)));

#define CAP 1536   // staged edge indices per block (block avg ~1024)

// ---------------- fused pre-pass: hist | conv x->f16+fp8 | conv W->f16 ----------------
__global__ __launch_bounds__(256) void pre_k(const float* __restrict__ x, u16* __restrict__ xh,
                                             u32* __restrict__ xq,
                                             const float* __restrict__ W, u16* __restrict__ wh,
                                             const int* __restrict__ dst, int E,
                                             u32* __restrict__ bktTotal, int N, int nbkt,
                                             int nba, int nbx) {
  int b = blockIdx.x, tid = threadIdx.x;
  if (b < nba) {                       // histogram over buckets (dst>>8)
    __shared__ u32 h[512];
    for (int t = tid; t < 512; t += 256) h[t] = 0u;
    __syncthreads();
    int base = b * 8192;
    for (int it = 0; it < 32; it++) {
      int i = base + it * 256 + tid;
      if (i < E) atomicAdd(&h[(u32)dst[i] >> 8], 1u);
    }
    __syncthreads();
    for (int t = tid; t < nbkt; t += 256) {
      u32 c = h[t];
      if (c) atomicAdd(&bktTotal[t], c);
    }
  } else if (b < nba + nbx) {          // x (N x 128 f32) -> f16 (GEMM) + fp8 (gather)
    int i = (b - nba) * 256 + tid;     // i-th float4
    if (i < N * 32) {
      const float4 v = *(const float4*)(x + (size_t)i * 4);
      u32 p0 = __builtin_bit_cast(u32, __builtin_amdgcn_cvt_pkrtz(v.x, v.y));
      u32 p1 = __builtin_bit_cast(u32, __builtin_amdgcn_cvt_pkrtz(v.z, v.w));
      *(uint2*)(xh + (size_t)i * 4) = uint2{p0, p1};
      u32 q = 0;
      q = __builtin_amdgcn_cvt_pk_fp8_f32(v.x, v.y, q, false);
      q = __builtin_amdgcn_cvt_pk_fp8_f32(v.z, v.w, q, true);
      xq[i] = q;
    }
  } else {                             // W (128 x 256 f32) -> f16
    int i = (b - nba - nbx) * 256 + tid;
    if (i < 8192) {
      const float4 v = *(const float4*)(W + (size_t)i * 4);
      u32 p0 = __builtin_bit_cast(u32, __builtin_amdgcn_cvt_pkrtz(v.x, v.y));
      u32 p1 = __builtin_bit_cast(u32, __builtin_amdgcn_cvt_pkrtz(v.z, v.w));
      *(uint2*)(wh + (size_t)i * 4) = uint2{p0, p1};
    }
  }
}

// ---------------- bucket scan: starts, cursors, offsets[N] ----------------
__global__ __launch_bounds__(512) void bscan_k(const u32* __restrict__ bktTotal, int nbkt,
                                               int E, int N, u32* __restrict__ start,
                                               u32* __restrict__ cursor, u32* __restrict__ offsets) {
  __shared__ u32 s[512];
  int t = threadIdx.x;
  u32 v = (t < nbkt) ? bktTotal[t] : 0u;
  s[t] = v;
  __syncthreads();
  for (int off = 1; off < 512; off <<= 1) {
    u32 x = (t >= off) ? s[t - off] : 0u;
    __syncthreads();
    s[t] += x;
    __syncthreads();
  }
  u32 excl = s[t] - v;
  if (t < nbkt) { start[t] = excl; cursor[t] = excl; }
  if (t == nbkt - 1) start[nbkt] = excl + v;   // == E
  if (t == 0) offsets[N] = (u32)E;
}

// ---------------- pass A2: partition edges into bucket regions (packed u32) ----------------
__global__ __launch_bounds__(256) void part_k(const int* __restrict__ src, const int* __restrict__ dst,
                                              int E, u32* __restrict__ cursor,
                                              u32* __restrict__ packed, int nbkt) {
  __shared__ u32 h[512];
  for (int t = threadIdx.x; t < 512; t += 256) h[t] = 0u;
  __syncthreads();
  int base = blockIdx.x * 8192;
  for (int it = 0; it < 32; it++) {
    int i = base + it * 256 + threadIdx.x;
    if (i < E) atomicAdd(&h[(u32)dst[i] >> 8], 1u);
  }
  __syncthreads();
  for (int t = threadIdx.x; t < nbkt; t += 256) {
    u32 c = h[t];
    h[t] = c ? atomicAdd(&cursor[t], c) : 0u;   // reserve contiguous per-(block,bucket) range
  }
  __syncthreads();
  for (int it = 0; it < 32; it++) {
    int i = base + it * 256 + threadIdx.x;
    if (i < E) {
      u32 d = (u32)dst[i];
      u32 pos = atomicAdd(&h[d >> 8], 1u);      // LDS atomic (u32 fast path)
      packed[pos] = (u32)src[i] | ((d & 255u) << 24);
    }
  }
}

// ---------------- pass B: counting sort -> offsets + ssrc + 32-node degree-rank perm ----------------
__global__ __launch_bounds__(256) void bucket_k(const u32* __restrict__ packed,
                                                const u32* __restrict__ start, int N,
                                                u32* __restrict__ offsets, int* __restrict__ ssrc,
                                                u8* __restrict__ nodeperm) {
  __shared__ u32 cnt[256];
  __shared__ u32 scn[256];
  __shared__ u32 cur[256];
  int b = blockIdx.x, t = threadIdx.x;
  u32 lo = start[b], hi = start[b + 1];
  cnt[t] = 0u;
  __syncthreads();
  for (u32 j = lo + t; j < hi; j += 256) atomicAdd(&cnt[packed[j] >> 24], 1u);
  __syncthreads();
  u32 v = cnt[t];
  scn[t] = v;
  __syncthreads();
  for (int off = 1; off < 256; off <<= 1) {
    u32 x = (t >= off) ? scn[t - off] : 0u;
    __syncthreads();
    scn[t] += x;
    __syncthreads();
  }
  u32 base = lo + scn[t] - v;     // exclusive position of this node's segment
  int node = b * 256 + t;
  if (node < N) offsets[node] = base;
  cur[t] = base;
  __syncthreads();
  for (u32 j = lo + t; j < hi; j += 256) {
    u32 w = packed[j];
    u32 pos = atomicAdd(&cur[w >> 24], 1u);   // LDS atomic (u32)
    ssrc[pos] = (int)(w & 0xFFFFFFu);
  }
  // degree-rank permutation per 32-node group (ascending degree, stable)
  {
    int g = t >> 5, l = t & 31;
    u32 mykey = cnt[t] * 256u + (u32)l;
    const u32* cg = &cnt[g * 32];
    u32 rank = 0;
#pragma unroll 8
    for (int l2 = 0; l2 < 32; l2++) {
      u32 k2 = cg[l2] * 256u + (u32)l2;
      rank += (k2 < mykey) ? 1u : 0u;
    }
    nodeperm[(size_t)b * 256 + g * 32 + rank] = (u8)l;
  }
}

// ---------------- fused aggregate + GEMM, 4 waves / 32 nodes per block ----------------
// Phase 1: block stages its edge indices in LDS (idx reads leave the vmcnt stream ->
// row loads pipeline freely); 16-lane sub-group per node, dwordx2 fp8 rows; 2-deep
// row-quad ping-pong (vA/vB) => consume A waits vmcnt(4) with B outstanding.
// Phase 2: 2 strips x 2 ct-halves; f16 MFMA: A = [xh rows | LDS means], B = wh.
#define DECV(vv) { f32x2 p;                                              \
    p = __builtin_amdgcn_cvt_pk_f32_fp8((vv).x, false); A0 += p;         \
    p = __builtin_amdgcn_cvt_pk_f32_fp8((vv).x, true);  A1 += p;         \
    p = __builtin_amdgcn_cvt_pk_f32_fp8((vv).y, false); A2 += p;         \
    p = __builtin_amdgcn_cvt_pk_f32_fp8((vv).y, true);  A3 += p; }

#define LOADQ(V0, V1, V2, V3, I) { \
    V0 = *(const uint2*)(xq + ((size_t)(I).x << 5) + (cl << 1)); \
    V1 = *(const uint2*)(xq + ((size_t)(I).y << 5) + (cl << 1)); \
    V2 = *(const uint2*)(xq + ((size_t)(I).z << 5) + (cl << 1)); \
    V3 = *(const uint2*)(xq + ((size_t)(I).w << 5) + (cl << 1)); }

#define CONSQ(V0, V1, V2, V3) { DECV(V0) DECV(V1) DECV(V2) DECV(V3) }

#define IDX4(O, DST) { if (inl) { int o_ = (int)(O); \
      DST.x = (u32)eidx[o_]; DST.y = (u32)eidx[o_ + 1]; \
      DST.z = (u32)eidx[o_ + 2]; DST.w = (u32)eidx[o_ + 3]; } \
    else DST = *(const uint4*)((const u32*)ssrc + S0 + (O)); }

__global__ __launch_bounds__(256) void fuse_k(const int* __restrict__ ssrc,
                                              const u32* __restrict__ offsets,
                                              const u32* __restrict__ xq,
                                              const u16* __restrict__ xh,
                                              const u16* __restrict__ wh,
                                              const float* __restrict__ bias,
                                              const u8* __restrict__ nodeperm,
                                              float* __restrict__ out, int N) {
  __shared__ int eidx[CAP];                   // staged edge indices (block-local)
  __shared__ u16 mlds[32][136];               // means (f16), padded stride
  int wv = threadIdx.x >> 6, lane = threadIdx.x & 63;
  int sub = lane >> 4, cl = lane & 15;
  int tid = threadIdx.x;
  int nbase = blockIdx.x * 32;

  // ---- stage edge indices into LDS (coalesced) ----
  u32 S0 = offsets[nbase];
  u32 S1 = offsets[nbase + 32 <= N ? nbase + 32 : N];
  int cntE = (int)(S1 - S0);
  int stg = cntE < CAP ? cntE : CAP;
  for (int i = tid * 4; i + 3 < stg; i += 1024)
    *(uint4*)&eidx[i] = *(const uint4*)(ssrc + S0 + i);
  {
    int base4 = stg & ~3;
    if (tid < (stg & 3)) eidx[base4 + tid] = ssrc[S0 + base4 + tid];
  }
  __syncthreads();

  // ---- phase 1: 2 rounds x 4 concurrent degree-matched nodes per wave ----
  for (int r = 0; r < 2; r++) {
    int ln = nodeperm[(size_t)nbase + r * 16 + wv * 4 + sub];
    int node = nbase + ln;
    f32x2 A0{0.f,0.f}, A1{0.f,0.f}, A2{0.f,0.f}, A3{0.f,0.f};
    u32 deg = 0;
    if (node < N) {
      u32 s0 = offsets[node], s1 = offsets[node + 1];
      deg = s1 - s0;
      const bool inl = ((s1 - S0) <= (u32)CAP);
      u32 lb0 = s0 - S0;                      // block-local offset
      u32 nq = deg >> 2;
      uint2 vA0, vA1, vA2, vA3, vB0, vB1, vB2, vB3;
      u32 j;
      if (nq >= 2) {
        uint4 iA, iB;
        IDX4(lb0, iA)
        IDX4(lb0 + 4, iB)
        LOADQ(vA0, vA1, vA2, vA3, iA)
        LOADQ(vB0, vB1, vB2, vB3, iB)
        u32 q = 2;
        for (; q + 1 < nq; q += 2) {
          uint4 i1, i2;
          IDX4(lb0 + q * 4, i1)
          IDX4(lb0 + q * 4 + 4, i2)
          CONSQ(vA0, vA1, vA2, vA3)           // waits vmcnt(4): B stays in flight
          LOADQ(vA0, vA1, vA2, vA3, i1)
          CONSQ(vB0, vB1, vB2, vB3)
          LOADQ(vB0, vB1, vB2, vB3, i2)
        }
        if (q < nq) {                          // one quad remains
          uint4 i1;
          IDX4(lb0 + q * 4, i1)
          CONSQ(vA0, vA1, vA2, vA3)
          LOADQ(vA0, vA1, vA2, vA3, i1)
          CONSQ(vB0, vB1, vB2, vB3)
          CONSQ(vA0, vA1, vA2, vA3)
          q++;
        } else {
          CONSQ(vA0, vA1, vA2, vA3)
          CONSQ(vB0, vB1, vB2, vB3)
        }
        j = s0 + nq * 4u;
      } else if (nq == 1) {
        uint4 iA;
        IDX4(lb0, iA)
        LOADQ(vA0, vA1, vA2, vA3, iA)
        CONSQ(vA0, vA1, vA2, vA3)
        j = s0 + 4u;
      } else {
        j = s0;
      }
      for (; j < s1; j++) {
        u32 o = j - S0;
        int e = inl ? eidx[o] : ssrc[j];
        uint2 v = *(const uint2*)(xq + ((size_t)e << 5) + (cl << 1));
        DECV(v)
      }
    }
    float inv = 1.0f / (float)(deg ? deg : 1u);
    u32 o0 = __builtin_bit_cast(u32, __builtin_amdgcn_cvt_pkrtz(A0.x * inv, A0.y * inv));
    u32 o1 = __builtin_bit_cast(u32, __builtin_amdgcn_cvt_pkrtz(A1.x * inv, A1.y * inv));
    u32 o2 = __builtin_bit_cast(u32, __builtin_amdgcn_cvt_pkrtz(A2.x * inv, A2.y * inv));
    u32 o3 = __builtin_bit_cast(u32, __builtin_amdgcn_cvt_pkrtz(A3.x * inv, A3.y * inv));
    *(uint4*)&mlds[ln][cl * 8] = uint4{o0, o1, o2, o3};   // 16 lanes cover 128 f16 feats
  }
  __syncthreads();

  // ---- phase 2: 2 strips x 2 col-halves; wave = (strip, half); f16 MFMA ----
  int la = lane & 15, lb = lane >> 4;
  int strip = wv & 1, ch = wv >> 1;
  int rbase = nbase + strip * 16;
  half8 a[8];
  const u16* ab = xh + ((size_t)(rbase + la) << 7) + lb * 8;
#pragma unroll
  for (int kb = 0; kb < 4; kb++) a[kb] = *(const half8*)(ab + kb * 32);
#pragma unroll
  for (int kb = 0; kb < 4; kb++)
    a[4 + kb] = *(const half8*)(&mlds[strip * 16 + la][kb * 32 + lb * 8]);

#pragma unroll
  for (int c = 0; c < 4; c++) {
    int ct = ch * 4 + c;
    f32x4 acc = { 0.f, 0.f, 0.f, 0.f };
    const u16* bbase = wh + ((size_t)(ct * 16 + la) << 8) + lb * 8;
#pragma unroll
    for (int kb = 0; kb < 8; kb++) {
      half8 b = *(const half8*)(bbase + kb * 32);
      acc = __builtin_amdgcn_mfma_f32_16x16x32_f16(a[kb], b, acc, 0, 0, 0);
    }
    float bc = bias[ct * 16 + la];
#pragma unroll
    for (int jj = 0; jj < 4; jj++) {
      int rr = rbase + lb * 4 + jj;
      if (rr < N) out[((size_t)rr << 7) + ct * 16 + la] = acc[jj] + bc;
    }
  }
}

extern "C" void kernel_launch(void* const* d_in, const int* in_sizes, int n_in,
                              void* d_out, int out_size, void* d_ws, size_t ws_size,
                              hipStream_t stream) {
  const float* x    = (const float*)d_in[0];
  const int*   ei   = (const int*)d_in[1];
  const float* W    = (const float*)d_in[2];
  const float* bias = (const float*)d_in[3];
  const int N = in_sizes[0] / 128;
  const int E = in_sizes[1] / 2;
  const int nbkt = (N + 255) >> 8;           // 256-node buckets
  const int* src = ei;
  const int* dst = ei + E;
  float* out = (float*)d_out;

  // transient CSR-build scratch in d_out (dead before fuse_k writes out):
  u32* packed   = (u32*)d_out;               // E
  u32* bktTotal = packed + E;                // nbkt
  u32* start    = bktTotal + nbkt;           // nbkt+1
  u32* cursor   = start + nbkt + 1;          // nbkt

  char* ws = (char*)d_ws;
  u32* offsets = (u32*)ws;                   // N+1
  size_t off = ((size_t)(N + 1) * 4 + 255) & ~(size_t)255;
  int* ssrc = (int*)(ws + off);              // E
  off += (size_t)E * 4;
  off = (off + 255) & ~(size_t)255;
  u16* xh = (u16*)(ws + off);                // N*128 f16 (GEMM A-half)
  off += (size_t)N * 128 * 2;
  off = (off + 255) & ~(size_t)255;
  u32* xq = (u32*)(ws + off);                // N*32 u32 (fp8 gather table)
  off += (size_t)N * 128;
  off = (off + 255) & ~(size_t)255;
  u16* wh = (u16*)(ws + off);                // 128*256 f16
  off += (size_t)128 * 256 * 2;
  off = (off + 255) & ~(size_t)255;
  u8* nodeperm = (u8*)(ws + off);            // nbkt*256 bytes

  const int nbx = (N * 32 + 255) / 256;
  const int nba = (E + 8191) / 8192;
  hipMemsetAsync(bktTotal, 0, (size_t)nbkt * 4, stream);
  pre_k<<<nba + nbx + 32, 256, 0, stream>>>(x, xh, xq, W, wh, dst, E, bktTotal, N, nbkt, nba, nbx);
  bscan_k<<<1, 512, 0, stream>>>(bktTotal, nbkt, E, N, start, cursor, offsets);
  part_k<<<nba, 256, 0, stream>>>(src, dst, E, cursor, packed, nbkt);
  bucket_k<<<nbkt, 256, 0, stream>>>(packed, start, N, offsets, ssrc, nodeperm);
  fuse_k<<<(N + 31) / 32, 256, 0, stream>>>(ssrc, offsets, xq, xh, wh, bias, nodeperm, out, N);
}